// Round 5
// baseline (159.518 us; speedup 1.0000x reference)
//
#include <hip/hip_runtime.h>

// SIAF forward, two fused MFMA GEMMs, zero h-transpose (permuted GEMM1 rows),
// bias-in-C, exp2-scaled tanh. Round 5: 16 samples/wave, 64/block, grid=2048
// -> 8 blocks/CU (32 waves/CU) for latency hiding; LDS 16KB/block.

#define DIMS 64

typedef __attribute__((ext_vector_type(8))) short short8;
typedef __attribute__((ext_vector_type(4))) float f32x4;
typedef __attribute__((ext_vector_type(4))) unsigned int uint4v;
typedef unsigned short ushort_t;
typedef unsigned int uint_t;

#if __has_builtin(__builtin_amdgcn_exp2f)
#define YSCALE 2.8853900817779268f      /* 2*log2(e): exp(2y) = exp2(YSCALE*y) */
#define EXPY(x) __builtin_amdgcn_exp2f(x)
#else
#define YSCALE 2.0f
#define EXPY(x) __expf(x)
#endif

__device__ __forceinline__ uint_t pk2bf(float a, float b) {
#if __has_builtin(__builtin_amdgcn_cvt_pk_bf16_f32)
    typedef __attribute__((ext_vector_type(2))) __bf16 bf16x2;
    bf16x2 r = __builtin_amdgcn_cvt_pk_bf16_f32(a, b);
    return __builtin_bit_cast(uint_t, r);
#else
    uint_t ua = __float_as_uint(a); ua += 0x7FFFu + ((ua >> 16) & 1u);
    uint_t ub = __float_as_uint(b); ub += 0x7FFFu + ((ub >> 16) & 1u);
    return (ub & 0xFFFF0000u) | (ua >> 16);
#endif
}

__device__ __forceinline__ ushort_t f2bf(float f) {
    uint_t u = __float_as_uint(f);
    u += 0x7FFFu + ((u >> 16) & 1u);
    return (ushort_t)(u >> 16);
}

// ws: w1b us[512*64] | w2full us[128*64] | b1f f[512] | b2f f[128]
#define W2F_OFF (512 * 64)
#define FREG_OFF (512 * 64 + 128 * 64)
#define PREP_N (512 * 64 + 128 * 64 + 512 + 128)

// logical row L for physical GEMM1 row p: window w=p>>5, tile parity e=(p>>4)&1,
// n=p&15 -> L = w*32 + (n>>2)*8 + e*4 + (n&3).  (l = L>>3, h = L&7)
__device__ __forceinline__ int logrow(int p) {
    int n = p & 15;
    return (p >> 5) * 32 + (n >> 2) * 8 + ((p >> 4) & 1) * 4 + (n & 3);
}

__global__ void siaf_prep(const float* __restrict__ W1, const float* __restrict__ b1,
                          const float* __restrict__ W2, const float* __restrict__ b2,
                          ushort_t* __restrict__ ws_u) {
    ushort_t* w1b    = ws_u;
    ushort_t* w2full = ws_u + W2F_OFF;
    float*    fb     = (float*)(ws_u + FREG_OFF);
    int i = blockIdx.x * 256 + threadIdx.x;
    if (i < 512 * 64) {
        int k = i & 63, p = i >> 6;
        int L = logrow(p), l = L >> 3, h = L & 7;
        float v = 0.0f;
        if (l < 63 && k <= l) v = W1[(l * 8 + h) * 63 + k] * YSCALE;
        w1b[i] = f2bf(v);
    } else if (i < FREG_OFF) {
        int j = i - W2F_OFF;
        int kl = j & 63, r = j >> 6, l = r >> 1, o = r & 1;
        float v = 0.0f;
        if (l < 63 && (kl >> 3) == (l & 7)) v = W2[(l * 2 + o) * 8 + (kl & 7)];
        w2full[j] = f2bf(v);
    } else if (i < FREG_OFF + 512) {
        int p = i - FREG_OFF;
        int L = logrow(p), l = L >> 3, h = L & 7;
        fb[p] = (l < 63) ? b1[l * 8 + h] * YSCALE : 0.0f;
    } else if (i < PREP_N) {
        int j = i - (FREG_OFF + 512);
        int l = j >> 1, o = j & 1;
        fb[512 + j] = (l < 63) ? b2[l * 2 + o] : 0.0f;
    }
}

__device__ __forceinline__ float th(float t) {
    // t = YSCALE*y ; tanh(y) = 1 - 2/(exp2(t)+1)
    float e = EXPY(t);
    float r = __builtin_amdgcn_rcpf(e + 1.0f);
    return fmaf(-2.0f, r, 1.0f);
}

__global__ __launch_bounds__(256, 8) void siaf_mfma(
        const float* __restrict__ x, const float* __restrict__ ip,
        const ushort_t* __restrict__ ws_u, float* __restrict__ out, int nB) {
    const ushort_t* w1b    = ws_u;
    const ushort_t* w2full = ws_u + W2F_OFF;
    const float*    b1f    = (const float*)(ws_u + FREG_OFF);
    const float*    b2f    = b1f + 512;

    __shared__ float xz[4][16 * 64];   // [wave][s_loc][64], 16B-chunk XOR swizzle

    const int tid  = threadIdx.x;
    const int wv   = tid >> 6, lane = tid & 63;
    const int s16  = lane & 15, quad = lane >> 4;
    const int sbase = blockIdx.x * 64 + wv * 16;

    float* xzw = xz[wv];

    // ---- phase 1: coalesced global -> LDS (1KB per wave instruction) ----
    #pragma unroll
    for (int g = 0; g < 4; ++g) {
        const float4 v = ((const float4*)(x + (size_t)(sbase + 4 * g) * DIMS))[lane];
        const int s_loc = 4 * g + quad;
        const int chunk = (lane & 15) ^ (s_loc & 15);
        *(float4*)(xzw + s_loc * 64 + chunk * 4) = v;
    }

    const float ip0 = ip[0], ip1 = ip[1];

    // ---- phase 2: x B-frag (bf16) from LDS ----
    short8 bfr[2];
    float lsum = 0.0f;
    #pragma unroll
    for (int kh = 0; kh < 2; ++kh) {
        const int c0 = kh * 8 + quad * 2;
        float4 va = *(const float4*)(xzw + s16 * 64 + ((c0 ^ s16) & 15) * 4);
        float4 vb = *(const float4*)(xzw + s16 * 64 + (((c0 + 1) ^ s16) & 15) * 4);
        uint4v u = {pk2bf(va.x, va.y), pk2bf(va.z, va.w),
                    pk2bf(vb.x, vb.y), pk2bf(vb.z, vb.w)};
        bfr[kh] = __builtin_bit_cast(short8, u);
    }

    for (int mt = 0; mt < 8; ++mt) {
        const ushort_t* w2p = w2full + (mt * 16 + s16) * 64 + quad * 8;
        f32x4 acc2 = {0.f, 0.f, 0.f, 0.f};

        #pragma unroll
        for (int half = 0; half < 2; ++half) {
            const int p0 = mt * 4 + half * 2;       // physical tile pair (e=0, e=1)
            const ushort_t* w1p0 = w1b + (p0 * 16 + s16) * 64 + quad * 8;
            const ushort_t* w1p1 = w1p0 + 1024;     // tile p0+1
            const short8 a00 = *(const short8*)w1p0;
            const short8 a10 = *(const short8*)w1p1;
            const float4 bi0 = *(const float4*)(b1f + p0 * 16 + quad * 4);
            const float4 bi1 = *(const float4*)(b1f + (p0 + 1) * 16 + quad * 4);
            const short8 c2 = *(const short8*)(w2p + half * 32);

            f32x4 aE = {bi0.x, bi0.y, bi0.z, bi0.w};
            f32x4 aO = {bi1.x, bi1.y, bi1.z, bi1.w};
            aE = __builtin_amdgcn_mfma_f32_16x16x32_bf16(a00, bfr[0], aE, 0, 0, 0);
            aO = __builtin_amdgcn_mfma_f32_16x16x32_bf16(a10, bfr[0], aO, 0, 0, 0);
            if (mt >= 4) {                          // rows with l>=32: upper k-half nonzero
                const short8 a01 = *(const short8*)(w1p0 + 32);
                const short8 a11 = *(const short8*)(w1p1 + 32);
                aE = __builtin_amdgcn_mfma_f32_16x16x32_bf16(a01, bfr[1], aE, 0, 0, 0);
                aO = __builtin_amdgcn_mfma_f32_16x16x32_bf16(a11, bfr[1], aO, 0, 0, 0);
            }
            // lane's own accs ARE its GEMM2 B-frag (row permutation in prep)
            uint4v hh = {pk2bf(th(aE[0]), th(aE[1])), pk2bf(th(aE[2]), th(aE[3])),
                         pk2bf(th(aO[0]), th(aO[1])), pk2bf(th(aO[2]), th(aO[3]))};
            const short8 hfr = __builtin_bit_cast(short8, hh);
            acc2 = __builtin_amdgcn_mfma_f32_16x16x32_bf16(c2, hfr, acc2, 0, 0, 0);
        }

        // ---- epilogue for l = mt*8 .. mt*8+7: z in-place in LDS ----
        const int l0 = mt * 8 + quad * 2;
        const float4 b2v = *(const float4*)(b2f + l0 * 2);
        const bool pad = (l0 == 62);                // l=63 slot is padding -> handles d=0
        float mu0 = acc2[0] + b2v.x, al0 = acc2[1] + b2v.y;
        float mu1 = acc2[2] + b2v.z, al1 = acc2[3] + b2v.w;
        const int d1 = l0 + 1;
        float* p1 = xzw + s16 * 64 + (((((d1 >> 2) ^ s16) & 15) << 2) | (d1 & 3));
        *p1 = fmaf(*p1, __expf(al0), mu0);
        lsum += al0;
        const float alB = pad ? ip1 : al1;
        const float muB = pad ? ip0 : mu1;
        const int d2 = pad ? 0 : (l0 + 2);
        float* p2 = xzw + s16 * 64 + (((((d2 >> 2) ^ s16) & 15) << 2) | (d2 & 3));
        *p2 = fmaf(*p2, __expf(alB), muB);
        lsum += alB;
    }

    // ---- phase 4: coalesced LDS -> global z store ----
    #pragma unroll
    for (int g = 0; g < 4; ++g) {
        const int s_loc = 4 * g + quad;
        const int chunk = (lane & 15) ^ (s_loc & 15);
        const float4 v = *(const float4*)(xzw + s_loc * 64 + chunk * 4);
        ((float4*)(out + (size_t)(sbase + 4 * g) * DIMS))[lane] = v;
    }

    // ---- log_det: sum the 4 quad-partials per sample ----
    {
        float v = lsum;
        int r1 = __builtin_amdgcn_ds_swizzle(__float_as_int(v), 0x401F);  // xor 16
        v += __int_as_float(r1);
        int r2 = __builtin_amdgcn_ds_bpermute((lane ^ 32) << 2, __float_as_int(v));
        v += __int_as_float(r2);
        if (quad == 0)
            out[(size_t)nB * DIMS + sbase + s16] = v;
    }
}

extern "C" void kernel_launch(void* const* d_in, const int* in_sizes, int n_in,
                              void* d_out, int out_size, void* d_ws, size_t ws_size,
                              hipStream_t stream) {
    const float* x  = (const float*)d_in[0];
    const float* ip = (const float*)d_in[1];
    const float* W1 = (const float*)d_in[2];
    const float* b1 = (const float*)d_in[3];
    const float* W2 = (const float*)d_in[4];
    const float* b2 = (const float*)d_in[5];
    ushort_t* ws = (ushort_t*)d_ws;
    float* out = (float*)d_out;

    const int nB = in_sizes[0] / DIMS;      // 131072

    siaf_prep<<<(PREP_N + 255) / 256, 256, 0, stream>>>(W1, b1, W2, b2, ws);
    siaf_mfma<<<nB / 64, 256, 0, stream>>>(x, ip, ws, out, nB);
}

// Round 6
// 134.394 us; speedup vs baseline: 1.1869x; 1.1869x over previous
//
#include <hip/hip_runtime.h>

// SIAF forward, two fused MFMA GEMMs, zero h-transpose (permuted GEMM1 rows),
// bias-in-C, exp2-scaled tanh.
// Round 6: 32 samples/wave (grid 1024, 4 blk/CU) + software-pipelined weight
// stream: 16 fully-unrolled (mt,half) groups with prefetch distance 1.
// launch_bounds(256,4) -> ~128 VGPR budget so cur+next weight groups stay
// resident (round-5 lesson: 32 VGPRs serializes every MFMA behind its load).

#define DIMS 64

typedef __attribute__((ext_vector_type(8))) short short8;
typedef __attribute__((ext_vector_type(4))) float f32x4;
typedef __attribute__((ext_vector_type(4))) unsigned int uint4v;
typedef unsigned short ushort_t;
typedef unsigned int uint_t;

#if __has_builtin(__builtin_amdgcn_exp2f)
#define YSCALE 2.8853900817779268f      /* 2*log2(e): exp(2y) = exp2(YSCALE*y) */
#define EXPY(x) __builtin_amdgcn_exp2f(x)
#else
#define YSCALE 2.0f
#define EXPY(x) __expf(x)
#endif

__device__ __forceinline__ uint_t pk2bf(float a, float b) {
#if __has_builtin(__builtin_amdgcn_cvt_pk_bf16_f32)
    typedef __attribute__((ext_vector_type(2))) __bf16 bf16x2;
    bf16x2 r = __builtin_amdgcn_cvt_pk_bf16_f32(a, b);
    return __builtin_bit_cast(uint_t, r);
#else
    uint_t ua = __float_as_uint(a); ua += 0x7FFFu + ((ua >> 16) & 1u);
    uint_t ub = __float_as_uint(b); ub += 0x7FFFu + ((ub >> 16) & 1u);
    return (ub & 0xFFFF0000u) | (ua >> 16);
#endif
}

__device__ __forceinline__ ushort_t f2bf(float f) {
    uint_t u = __float_as_uint(f);
    u += 0x7FFFu + ((u >> 16) & 1u);
    return (ushort_t)(u >> 16);
}

// ws: w1b us[512*64] | w2full us[128*64] | b1f f[512] | b2f f[128]
#define W2F_OFF (512 * 64)
#define FREG_OFF (512 * 64 + 128 * 64)
#define PREP_N (512 * 64 + 128 * 64 + 512 + 128)

// logical row L for physical GEMM1 row p: window w=p>>5, tile parity e=(p>>4)&1,
// n=p&15 -> L = w*32 + (n>>2)*8 + e*4 + (n&3).  (l = L>>3, h = L&7)
__device__ __forceinline__ int logrow(int p) {
    int n = p & 15;
    return (p >> 5) * 32 + (n >> 2) * 8 + ((p >> 4) & 1) * 4 + (n & 3);
}

__global__ void siaf_prep(const float* __restrict__ W1, const float* __restrict__ b1,
                          const float* __restrict__ W2, const float* __restrict__ b2,
                          ushort_t* __restrict__ ws_u) {
    ushort_t* w1b    = ws_u;
    ushort_t* w2full = ws_u + W2F_OFF;
    float*    fb     = (float*)(ws_u + FREG_OFF);
    int i = blockIdx.x * 256 + threadIdx.x;
    if (i < 512 * 64) {
        int k = i & 63, p = i >> 6;
        int L = logrow(p), l = L >> 3, h = L & 7;
        float v = 0.0f;
        if (l < 63 && k <= l) v = W1[(l * 8 + h) * 63 + k] * YSCALE;
        w1b[i] = f2bf(v);
    } else if (i < FREG_OFF) {
        int j = i - W2F_OFF;
        int kl = j & 63, r = j >> 6, l = r >> 1, o = r & 1;
        float v = 0.0f;
        if (l < 63 && (kl >> 3) == (l & 7)) v = W2[(l * 2 + o) * 8 + (kl & 7)];
        w2full[j] = f2bf(v);
    } else if (i < FREG_OFF + 512) {
        int p = i - FREG_OFF;
        int L = logrow(p), l = L >> 3, h = L & 7;
        fb[p] = (l < 63) ? b1[l * 8 + h] * YSCALE : 0.0f;
    } else if (i < PREP_N) {
        int j = i - (FREG_OFF + 512);
        int l = j >> 1, o = j & 1;
        fb[512 + j] = (l < 63) ? b2[l * 2 + o] : 0.0f;
    }
}

__device__ __forceinline__ float th(float t) {
    // t = YSCALE*y ; tanh(y) = 1 - 2/(exp2(t)+1)
    float e = EXPY(t);
    float r = __builtin_amdgcn_rcpf(e + 1.0f);
    return fmaf(-2.0f, r, 1.0f);
}

struct Grp {
    short8 a00, a10, a01, a11, c2;
    float4 bi0, bi1;
};

__device__ __forceinline__ Grp load_grp(int g, const ushort_t* __restrict__ w1b,
                                        const ushort_t* __restrict__ w2full,
                                        const float* __restrict__ b1f,
                                        int s16, int quad) {
    Grp r;
    const int p0 = 2 * g;
    const ushort_t* w1p0 = w1b + (p0 * 16 + s16) * 64 + quad * 8;
    r.a00 = *(const short8*)w1p0;
    r.a10 = *(const short8*)(w1p0 + 1024);
    if (g >= 8) {                        // rows with l>=32: upper k-half nonzero
        r.a01 = *(const short8*)(w1p0 + 32);
        r.a11 = *(const short8*)(w1p0 + 1024 + 32);
    }
    r.c2  = *(const short8*)(w2full + ((g >> 1) * 16 + s16) * 64 + quad * 8 + (g & 1) * 32);
    r.bi0 = *(const float4*)(b1f + p0 * 16 + quad * 4);
    r.bi1 = *(const float4*)(b1f + (p0 + 1) * 16 + quad * 4);
    return r;
}

__global__ __launch_bounds__(256, 4) void siaf_mfma(
        const float* __restrict__ x, const float* __restrict__ ip,
        const ushort_t* __restrict__ ws_u, float* __restrict__ out, int nB) {
    const ushort_t* w1b    = ws_u;
    const ushort_t* w2full = ws_u + W2F_OFF;
    const float*    b1f    = (const float*)(ws_u + FREG_OFF);
    const float*    b2f    = b1f + 512;

    __shared__ float xz[4][32 * 64];   // [wave][s_loc][64], 16B-chunk XOR swizzle

    const int tid  = threadIdx.x;
    const int wv   = tid >> 6, lane = tid & 63;
    const int s16  = lane & 15, quad = lane >> 4;
    const int sbase = blockIdx.x * 128 + wv * 32;

    float* xzw = xz[wv];

    // ---- phase 1: coalesced global -> LDS (1KB per wave instruction) ----
    #pragma unroll
    for (int g = 0; g < 8; ++g) {
        const float4 v = ((const float4*)(x + (size_t)(sbase + 4 * g) * DIMS))[lane];
        const int s_loc = 4 * g + quad;
        const int chunk = (lane & 15) ^ (s_loc & 15);
        *(float4*)(xzw + s_loc * 64 + chunk * 4) = v;
    }

    const float ip0 = ip[0], ip1 = ip[1];

    // ---- phase 2: x B-frags (bf16) from LDS ----
    short8 bfr[2][2];
    float lsum[2] = {0.0f, 0.0f};
    #pragma unroll
    for (int st = 0; st < 2; ++st) {
        const int s_loc = st * 16 + s16;
        #pragma unroll
        for (int kh = 0; kh < 2; ++kh) {
            const int c0 = kh * 8 + quad * 2;
            float4 va = *(const float4*)(xzw + s_loc * 64 + ((c0 ^ s16) & 15) * 4);
            float4 vb = *(const float4*)(xzw + s_loc * 64 + (((c0 + 1) ^ s16) & 15) * 4);
            uint4v u = {pk2bf(va.x, va.y), pk2bf(va.z, va.w),
                        pk2bf(vb.x, vb.y), pk2bf(vb.z, vb.w)};
            bfr[st][kh] = __builtin_bit_cast(short8, u);
        }
    }

    // ---- fused K-loop: 16 (mt,half) groups, prefetch distance 1 ----
    Grp cur = load_grp(0, w1b, w2full, b1f, s16, quad);
    f32x4 acc2[2];
    #pragma unroll
    for (int g = 0; g < 16; ++g) {
        Grp nxt;
        if (g < 15) nxt = load_grp(g + 1, w1b, w2full, b1f, s16, quad);

        #pragma unroll
        for (int st = 0; st < 2; ++st) {
            f32x4 aE = {cur.bi0.x, cur.bi0.y, cur.bi0.z, cur.bi0.w};
            f32x4 aO = {cur.bi1.x, cur.bi1.y, cur.bi1.z, cur.bi1.w};
            aE = __builtin_amdgcn_mfma_f32_16x16x32_bf16(cur.a00, bfr[st][0], aE, 0, 0, 0);
            aO = __builtin_amdgcn_mfma_f32_16x16x32_bf16(cur.a10, bfr[st][0], aO, 0, 0, 0);
            if (g >= 8) {
                aE = __builtin_amdgcn_mfma_f32_16x16x32_bf16(cur.a01, bfr[st][1], aE, 0, 0, 0);
                aO = __builtin_amdgcn_mfma_f32_16x16x32_bf16(cur.a11, bfr[st][1], aO, 0, 0, 0);
            }
            // lane's own accs ARE its GEMM2 B-frag (row permutation in prep)
            uint4v hh = {pk2bf(th(aE[0]), th(aE[1])), pk2bf(th(aE[2]), th(aE[3])),
                         pk2bf(th(aO[0]), th(aO[1])), pk2bf(th(aO[2]), th(aO[3]))};
            const short8 hfr = __builtin_bit_cast(short8, hh);
            f32x4 a2 = (g & 1) ? acc2[st] : f32x4{0.f, 0.f, 0.f, 0.f};
            acc2[st] = __builtin_amdgcn_mfma_f32_16x16x32_bf16(cur.c2, hfr, a2, 0, 0, 0);
        }

        if (g & 1) {
            // ---- epilogue for l = mt*8 .. mt*8+7: z in-place in LDS ----
            const int mt = g >> 1;
            const int l0 = mt * 8 + quad * 2;
            const float4 b2v = *(const float4*)(b2f + l0 * 2);
            const bool pad = (l0 == 62);            // l=63 slot handles d=0 instead
            #pragma unroll
            for (int st = 0; st < 2; ++st) {
                const int s_loc = st * 16 + s16;
                float mu0 = acc2[st][0] + b2v.x, al0 = acc2[st][1] + b2v.y;
                float mu1 = acc2[st][2] + b2v.z, al1 = acc2[st][3] + b2v.w;
                const int d1 = l0 + 1;
                float* p1 = xzw + s_loc * 64 + (((((d1 >> 2) ^ s16) & 15) << 2) | (d1 & 3));
                *p1 = fmaf(*p1, __expf(al0), mu0);
                lsum[st] += al0;
                const float alB = pad ? ip1 : al1;
                const float muB = pad ? ip0 : mu1;
                const int d2 = pad ? 0 : (l0 + 2);
                float* p2 = xzw + s_loc * 64 + (((((d2 >> 2) ^ s16) & 15) << 2) | (d2 & 3));
                *p2 = fmaf(*p2, __expf(alB), muB);
                lsum[st] += alB;
            }
        }
        cur = nxt;
    }

    // ---- phase 4: coalesced LDS -> global z store ----
    #pragma unroll
    for (int g = 0; g < 8; ++g) {
        const int s_loc = 4 * g + quad;
        const int chunk = (lane & 15) ^ (s_loc & 15);
        const float4 v = *(const float4*)(xzw + s_loc * 64 + chunk * 4);
        ((float4*)(out + (size_t)(sbase + 4 * g) * DIMS))[lane] = v;
    }

    // ---- log_det: sum the 4 quad-partials per sample ----
    #pragma unroll
    for (int st = 0; st < 2; ++st) {
        float v = lsum[st];
        int r1 = __builtin_amdgcn_ds_swizzle(__float_as_int(v), 0x401F);  // xor 16
        v += __int_as_float(r1);
        int r2 = __builtin_amdgcn_ds_bpermute((lane ^ 32) << 2, __float_as_int(v));
        v += __int_as_float(r2);
        if (quad == 0)
            out[(size_t)nB * DIMS + sbase + st * 16 + s16] = v;
    }
}

extern "C" void kernel_launch(void* const* d_in, const int* in_sizes, int n_in,
                              void* d_out, int out_size, void* d_ws, size_t ws_size,
                              hipStream_t stream) {
    const float* x  = (const float*)d_in[0];
    const float* ip = (const float*)d_in[1];
    const float* W1 = (const float*)d_in[2];
    const float* b1 = (const float*)d_in[3];
    const float* W2 = (const float*)d_in[4];
    const float* b2 = (const float*)d_in[5];
    ushort_t* ws = (ushort_t*)d_ws;
    float* out = (float*)d_out;

    const int nB = in_sizes[0] / DIMS;      // 131072

    siaf_prep<<<(PREP_N + 255) / 256, 256, 0, stream>>>(W1, b1, W2, b2, ws);
    siaf_mfma<<<nB / 128, 256, 0, stream>>>(x, ip, ws, out, nB);
}

// Round 7
// 112.142 us; speedup vs baseline: 1.4225x; 1.1984x over previous
//
#include <hip/hip_runtime.h>

// SIAF forward. Round 7: ALL weights staged once per block into LDS (56 KB image,
// prepared in final swizzled layout by prep kernel); GEMM1 = permuted-row MFMA
// (lane ends up owning the full 8-wide hidden vector of layer l=4w+quad);
// GEMM2 = 16 fp32 FMAs against broadcast LDS reads (no second MFMA, no packing).
// 1024-thread blocks (16 waves x 16 samples), dynamic LDS 119 KB -> 1 block/CU.
// Rounds 4-6 lesson: compiler won't hold VMEM weight prefetches in registers
// (VGPR stayed 64, spills appeared); LDS staging is the structural fix.

#define DIMS 64
#define TPB  1024
#define WAVES 16
#define SPW  16

typedef __attribute__((ext_vector_type(8))) short short8;
typedef __attribute__((ext_vector_type(4))) float f32x4;
typedef __attribute__((ext_vector_type(4))) unsigned int uint4v;
typedef unsigned short ushort_t;
typedef unsigned int uint_t;

#if __has_builtin(__builtin_amdgcn_exp2f)
#define YSCALE 2.8853900817779268f      /* 2*log2(e): exp(2y) = exp2(YSCALE*y) */
#define EXPY(x) __builtin_amdgcn_exp2f(x)
#else
#define YSCALE 2.0f
#define EXPY(x) __expf(x)
#endif

// LDS/ws image layout (bytes):
//  A [0,16384):      w1 rows 0..255 (l<32), 64 B/row (k<32 only), 4-chunk XOR swizzle
//  B [16384,49152):  w1 rows 256..511, 128 B/row, 8-chunk XOR swizzle
//  C [49152,53248):  W2 fp32 [64 l][2 o][8 h]
//  D [53248,55296):  b1 fp32 [512] in physical (permuted) row order, YSCALE-scaled
//  E [55296,55808):  b2 fp32 [64][2]
#define A_OFF 0
#define B_OFF 16384
#define C_OFF 49152
#define D_OFF 53248
#define E_OFF 55296
#define WT_BYTES 55808
#define WT_CHUNKS (WT_BYTES / 16)
#define XZ_OFF WT_BYTES
#define LDS_BYTES (WT_BYTES + WAVES * SPW * DIMS * 4)   // 55808 + 65536 = 121344
#define PREP_N (24576 + 1664)

__device__ __forceinline__ uint_t pk2bf(float a, float b) {
#if __has_builtin(__builtin_amdgcn_cvt_pk_bf16_f32)
    typedef __attribute__((ext_vector_type(2))) __bf16 bf16x2;
    bf16x2 r = __builtin_amdgcn_cvt_pk_bf16_f32(a, b);
    return __builtin_bit_cast(uint_t, r);
#else
    uint_t ua = __float_as_uint(a); ua += 0x7FFFu + ((ua >> 16) & 1u);
    uint_t ub = __float_as_uint(b); ub += 0x7FFFu + ((ub >> 16) & 1u);
    return (ub & 0xFFFF0000u) | (ua >> 16);
#endif
}

__device__ __forceinline__ ushort_t f2bf(float f) {
    uint_t u = __float_as_uint(f);
    u += 0x7FFFu + ((u >> 16) & 1u);
    return (ushort_t)(u >> 16);
}

// logical row L for physical GEMM1 row p (window w=p>>5, tile parity e=(p>>4)&1,
// n=p&15): L = w*32 + (n>>2)*8 + e*4 + (n&3);  l = L>>3, h = L&7.
__device__ __forceinline__ int logrow(int p) {
    int n = p & 15;
    return (p >> 5) * 32 + (n >> 2) * 8 + ((p >> 4) & 1) * 4 + (n & 3);
}

__global__ void siaf_prep(const float* __restrict__ W1, const float* __restrict__ b1,
                          const float* __restrict__ W2, const float* __restrict__ b2,
                          ushort_t* __restrict__ ws_u) {
    int i = blockIdx.x * 256 + threadIdx.x;
    if (i < 8192) {                       // region A: p<256, 32 ushorts/row
        int p = i >> 5, e = i & 31;
        int cp = e >> 3, j = e & 7;
        int k = ((cp ^ (p & 3)) << 3) | j;          // de-swizzled logical k (<32)
        int L = logrow(p), l = L >> 3, h = L & 7;
        float v = (k <= l) ? W1[(l * 8 + h) * 63 + k] * YSCALE : 0.0f;
        ws_u[i] = f2bf(v);
    } else if (i < 24576) {               // region B: p in [256,512), 64 ushorts/row
        int v_ = i - 8192;
        int p = 256 + (v_ >> 6), e = v_ & 63;
        int cp = e >> 3, j = e & 7;
        int k = ((cp ^ (p & 7)) << 3) | j;
        int L = logrow(p), l = L >> 3, h = L & 7;
        float v = (l < 63 && k <= l) ? W1[(l * 8 + h) * 63 + k] * YSCALE : 0.0f;
        ws_u[i] = f2bf(v);
    } else if (i < PREP_N) {              // fp32 regions C/D/E
        int f = i - 24576;
        float* fws = (float*)(ws_u + 24576);
        float v = 0.0f;
        if (f < 1024) {                   // C: W2 [l][o][h]
            int l = f >> 4, o = (f >> 3) & 1, h = f & 7;
            if (l < 63) v = W2[(l * 2 + o) * 8 + h];
        } else if (f < 1536) {            // D: b1 in physical row order
            int p = f - 1024;
            int L = logrow(p), l = L >> 3, h = L & 7;
            if (l < 63) v = b1[l * 8 + h] * YSCALE;
        } else {                          // E: b2 [l][o]
            int j = f - 1536, l = j >> 1, o = j & 1;
            if (l < 63) v = b2[l * 2 + o];
        }
        fws[f] = v;
    }
}

__device__ __forceinline__ float th(float t) {
    // t = YSCALE*y ; tanh(y) = 1 - 2/(exp2(t)+1)
    float e = EXPY(t);
    float r = __builtin_amdgcn_rcpf(e + 1.0f);
    return fmaf(-2.0f, r, 1.0f);
}

__global__ __launch_bounds__(TPB, 4) void siaf_main(
        const float* __restrict__ x, const float* __restrict__ ip,
        const uint4* __restrict__ wsv, float* __restrict__ out, int nB) {
    extern __shared__ unsigned char lds[];

    // ---- stage the 56 KB weight image (already in final layout) ----
    {
        uint4* dst = (uint4*)lds;
        for (int c = threadIdx.x; c < WT_CHUNKS; c += TPB) dst[c] = wsv[c];
    }
    __syncthreads();

    const ushort_t* wA  = (const ushort_t*)(lds + A_OFF);
    const ushort_t* wB  = (const ushort_t*)(lds + B_OFF);
    const float*    w2f = (const float*)(lds + C_OFF);
    const float*    b1f = (const float*)(lds + D_OFF);
    const float*    b2f = (const float*)(lds + E_OFF);

    const int tid  = threadIdx.x;
    const int wv   = tid >> 6, lane = tid & 63;
    const int s16  = lane & 15, quad = lane >> 4;
    const int sbase = blockIdx.x * (WAVES * SPW) + wv * SPW;
    float* xzw = (float*)(lds + XZ_OFF) + wv * (SPW * DIMS);

    // ---- stage x: coalesced 1KB/instr, 16B-chunk XOR swizzle (key = row) ----
    #pragma unroll
    for (int g = 0; g < 4; ++g) {
        const float4 v = ((const float4*)(x + (size_t)sbase * DIMS))[g * 64 + lane];
        const int s_loc = 4 * g + quad;
        const int pc = (s16 ^ s_loc) & 15;
        *(float4*)(xzw + s_loc * 64 + pc * 4) = v;
    }
    const float ip0 = ip[0], ip1 = ip[1];

    // ---- B-frag: B[k=quad*8+j][n=s16] from LDS, bf16 ----
    short8 bfr[2];
    #pragma unroll
    for (int kh = 0; kh < 2; ++kh) {
        const int c0 = kh * 8 + quad * 2;
        float4 va = *(const float4*)(xzw + s16 * 64 + ((c0 ^ s16) & 15) * 4);
        float4 vb = *(const float4*)(xzw + s16 * 64 + (((c0 + 1) ^ s16) & 15) * 4);
        uint4v u = {pk2bf(va.x, va.y), pk2bf(va.z, va.w),
                    pk2bf(vb.x, vb.y), pk2bf(vb.z, vb.w)};
        bfr[kh] = __builtin_bit_cast(short8, u);
    }

    float lsum = 0.0f;
    #pragma unroll
    for (int w = 0; w < 16; ++w) {
        // A-frags from LDS (bank-balanced XOR-swizzled rows)
        short8 a00, a10, a01{}, a11{};
        if (w < 8) {
            const ushort_t* base = wA + (w * 32 + s16) * 32;   // 64 B rows
            const int pc = quad ^ (s16 & 3);
            a00 = *(const short8*)(base + pc * 8);
            a10 = *(const short8*)(base + 512 + pc * 8);       // +16 rows
        } else {
            const ushort_t* base = wB + ((w - 8) * 32 + s16) * 64;  // 128 B rows
            const int pc = quad ^ (s16 & 7);
            a00 = *(const short8*)(base + pc * 8);
            a10 = *(const short8*)(base + 1024 + pc * 8);
            a01 = *(const short8*)(base + (pc ^ 4) * 8);
            a11 = *(const short8*)(base + 1024 + (pc ^ 4) * 8);
        }
        const float4 bi0 = *(const float4*)(b1f + w * 32 + quad * 4);       // broadcast
        const float4 bi1 = *(const float4*)(b1f + w * 32 + 16 + quad * 4);  // broadcast

        f32x4 aE = {bi0.x, bi0.y, bi0.z, bi0.w};
        f32x4 aO = {bi1.x, bi1.y, bi1.z, bi1.w};
        aE = __builtin_amdgcn_mfma_f32_16x16x32_bf16(a00, bfr[0], aE, 0, 0, 0);
        aO = __builtin_amdgcn_mfma_f32_16x16x32_bf16(a10, bfr[0], aO, 0, 0, 0);
        if (w >= 8) {
            aE = __builtin_amdgcn_mfma_f32_16x16x32_bf16(a01, bfr[1], aE, 0, 0, 0);
            aO = __builtin_amdgcn_mfma_f32_16x16x32_bf16(a11, bfr[1], aO, 0, 0, 0);
        }

        // lane owns layer l = 4w+quad, sample s16: full hidden vector
        const float t0 = th(aE[0]), t1 = th(aE[1]), t2 = th(aE[2]), t3 = th(aE[3]);
        const float t4 = th(aO[0]), t5 = th(aO[1]), t6 = th(aO[2]), t7 = th(aO[3]);

        const int l = 4 * w + quad;
        const float4 m0 = *(const float4*)(w2f + l * 16);        // broadcast reads
        const float4 m1 = *(const float4*)(w2f + l * 16 + 4);
        const float4 a0 = *(const float4*)(w2f + l * 16 + 8);
        const float4 a1 = *(const float4*)(w2f + l * 16 + 12);
        const float2 bb = *(const float2*)(b2f + l * 2);

        float mu = bb.x;
        mu = fmaf(m0.x, t0, mu); mu = fmaf(m0.y, t1, mu);
        mu = fmaf(m0.z, t2, mu); mu = fmaf(m0.w, t3, mu);
        mu = fmaf(m1.x, t4, mu); mu = fmaf(m1.y, t5, mu);
        mu = fmaf(m1.z, t6, mu); mu = fmaf(m1.w, t7, mu);
        float al = bb.y;
        al = fmaf(a0.x, t0, al); al = fmaf(a0.y, t1, al);
        al = fmaf(a0.z, t2, al); al = fmaf(a0.w, t3, al);
        al = fmaf(a1.x, t4, al); al = fmaf(a1.y, t5, al);
        al = fmaf(a1.z, t6, al); al = fmaf(a1.w, t7, al);

        // epilogue: z[d=l+1] in-place in LDS (l=63 pad lane handles d=0 instead)
        const bool pad = (l == 63);
        const float alB = pad ? ip1 : al;
        const float muB = pad ? ip0 : mu;
        const int d = pad ? 0 : (l + 1);
        float* pz = xzw + s16 * 64 + ((((d >> 2) ^ s16) & 15) << 2) + (d & 3);
        *pz = fmaf(*pz, __expf(alB), muB);
        lsum += alB;
    }

    // ---- coalesced LDS -> global z store ----
    #pragma unroll
    for (int g = 0; g < 4; ++g) {
        const int s_loc = 4 * g + quad;
        const int pc = (s16 ^ s_loc) & 15;
        const float4 v = *(const float4*)(xzw + s_loc * 64 + pc * 4);
        ((float4*)(out + (size_t)sbase * DIMS))[g * 64 + lane] = v;
    }

    // ---- log_det: sum the 4 quad-partials per sample ----
    {
        float v = lsum;
        int r1 = __builtin_amdgcn_ds_swizzle(__float_as_int(v), 0x401F);  // xor 16
        v += __int_as_float(r1);
        int r2 = __builtin_amdgcn_ds_bpermute((lane ^ 32) << 2, __float_as_int(v));
        v += __int_as_float(r2);
        if (quad == 0)
            out[(size_t)nB * DIMS + sbase + s16] = v;
    }
}

extern "C" void kernel_launch(void* const* d_in, const int* in_sizes, int n_in,
                              void* d_out, int out_size, void* d_ws, size_t ws_size,
                              hipStream_t stream) {
    const float* x  = (const float*)d_in[0];
    const float* ip = (const float*)d_in[1];
    const float* W1 = (const float*)d_in[2];
    const float* b1 = (const float*)d_in[3];
    const float* W2 = (const float*)d_in[4];
    const float* b2 = (const float*)d_in[5];
    ushort_t* ws = (ushort_t*)d_ws;
    float* out = (float*)d_out;

    const int nB = in_sizes[0] / DIMS;      // 131072

    static bool attr_done = false;
    (void)hipFuncSetAttribute((const void*)siaf_main,
                              hipFuncAttributeMaxDynamicSharedMemorySize, LDS_BYTES);
    (void)attr_done;

    siaf_prep<<<(PREP_N + 255) / 256, 256, 0, stream>>>(W1, b1, W2, b2, ws);
    siaf_main<<<nB / (WAVES * SPW), TPB, LDS_BYTES, stream>>>(
        x, ip, (const uint4*)ws, out, nB);
}